// Round 14
// baseline (66.467 us; speedup 1.0000x reference)
//
#include <hip/hip_runtime.h>
#include <math.h>

constexpr int B_ = 4096, T_ = 200, D_ = 64;
constexpr float NEG_INF_F = -4294967295.0f;  // float32(-2^32+1)
constexpr float LOG2E = 1.4426950408889634f;

typedef __attribute__((ext_vector_type(8))) __bf16 bf16x8;
typedef __attribute__((ext_vector_type(4))) float f32x4;

__device__ __host__ inline unsigned short f2b_rne(float x) {
    unsigned u = __builtin_bit_cast(unsigned, x);
    u += 0x7FFF + ((u >> 16) & 1);
    return (unsigned short)(u >> 16);
}

__device__ inline unsigned short b16bits(float x) {
    return __builtin_bit_cast(unsigned short, (__bf16)x);
}

__device__ inline float frcp(float x) { return __builtin_amdgcn_rcpf(x); }

__device__ inline float fexp2(float x) {
#if __has_builtin(__builtin_amdgcn_exp2f)
    return __builtin_amdgcn_exp2f(x);
#else
    return exp2f(x);
#endif
}

__device__ inline bf16x8 pack8(float4 lo, float4 hi) {
    bf16x8 r;
    r[0] = (__bf16)lo.x; r[1] = (__bf16)lo.y; r[2] = (__bf16)lo.z; r[3] = (__bf16)lo.w;
    r[4] = (__bf16)hi.x; r[5] = (__bf16)hi.y; r[6] = (__bf16)hi.z; r[7] = (__bf16)hi.w;
    return r;
}

// ---------------------------------------------------------------------------
// Fold weights into MFMA-fragment order (bf16), PRE-SCALED by log2(e).
// ---------------------------------------------------------------------------
__global__ void fold_weights(const float* __restrict__ W1,
                             const float* __restrict__ W2,
                             unsigned short* __restrict__ w1f,
                             unsigned short* __restrict__ w2f,
                             unsigned short* __restrict__ wqff) {
    int i = blockIdx.x * blockDim.x + threadIdx.x;
    if (i < 10240) {
        int j = i & 7, lane = (i >> 3) & 63, nt = (i >> 9) % 5, s = i / 2560;
        int k = s * 32 + (lane >> 4) * 8 + j;
        int n = nt * 16 + (lane & 15);
        float v = (k < 64) ? W1[(64 + k) * 80 + n] - W1[(128 + k) * 80 + n]
                           : W1[(192 + (k - 64)) * 80 + n];
        w1f[i] = f2b_rne(v * LOG2E);
    } else if (i < 14848) {
        int i2 = i - 10240;
        int j = i2 & 7, lane = (i2 >> 3) & 63, nt = (i2 >> 9) % 3, s = i2 / 1536;
        int k = s * 32 + (lane >> 4) * 8 + j;
        int n = nt * 16 + (lane & 15);
        float v = (k < 80 && n < 40) ? W2[k * 40 + n] * LOG2E : 0.f;
        w2f[i2] = f2b_rne(v);
    } else if (i < 19968) {
        int i3 = i - 14848;
        int j = i3 & 7, lane = (i3 >> 3) & 63, nt = (i3 >> 9) % 5, s = i3 / 2560;
        int d = s * 32 + (lane >> 4) * 8 + j;
        int n = nt * 16 + (lane & 15);
        wqff[i3] = f2b_rne((W1[d * 80 + n] + W1[(128 + d) * 80 + n]) * LOG2E);
    }
}

// ---------------------------------------------------------------------------
// Main kernel: ONE ROW PER BLOCK, TWO WAVES PER ROW (128 threads).
// Round 13 was drain-bound: grid == residency capacity, so short-row waves
// retired into empty slots while 13-tile rows finished alone. Now: wave w
// does tiles [w? nt0:0, w? ntile:nt0), output [w? mid:0, w? obound:mid);
// LDS 14.8KB/block -> ~10 blocks/CU capacity vs 16 demand -> real backfill,
// and the longest block's critical path halves. Prologue (hinit MFMAs +
// W_eff build) duplicated per wave; softmax redundantly computed per wave
// (same-value write-back, round-8-verified).
// ---------------------------------------------------------------------------
__global__ __launch_bounds__(128, 2)
void din_attn(const float* __restrict__ q, const float* __restrict__ keys,
              const int* __restrict__ klen,
              const unsigned short* __restrict__ w1f,
              const unsigned short* __restrict__ w2f,
              const unsigned short* __restrict__ wqff,
              const float* __restrict__ b1, const float* __restrict__ b2,
              const float* __restrict__ W3, const float* __restrict__ b3,
              float* __restrict__ out) {
    const int tid = threadIdx.x;
    const int l = tid & 63, w = tid >> 6, g4 = l >> 4, ln = l & 15;
    const int b = blockIdx.x;

    alignas(16) __shared__ unsigned short h1c[2][2][16 * 104]; // 13.3 KB
    __shared__ float red[256];                                 // 1 KB
    __shared__ float opart[2][64];                             // 0.5 KB

    constexpr float NEGS = NEG_INF_F * (0.125f * LOG2E);

    unsigned short* buf0 = h1c[w][0];
    unsigned short* buf1 = h1c[w][1];
    // init all logits to masked constant; pads 200..255 to -inf
    red[tid] = NEGS;
    red[128 + tid] = (128 + tid < 200) ? NEGS : -INFINITY;
    #pragma unroll
    for (int r = 0; r < 4; ++r) {             // zero pad cols 80..95 once
        buf0[(g4 * 4 + r) * 104 + 80 + ln] = 0;
        buf1[(g4 * 4 + r) * 104 + 80 + ln] = 0;
    }

    const int len = klen[b];
    const int ntile = (len + 15) >> 4;        // 0..13 active tiles
    const int nt0 = (ntile + 1) >> 1;
    const int ts = w ? nt0 : 0;
    const int te = w ? ntile : nt0;
    const float b3v = b3[0];
    const float* kb = keys + (size_t)b * 200 * 64;

#define LOADK(tile_, B0_, B1_, B2_, B3_) do {                              \
        int t_ = (tile_) * 16 + ln;                                        \
        int tc_ = t_ < 200 ? t_ : 199;                                     \
        const float* row_ = kb + tc_ * 64 + g4 * 8;                        \
        B0_ = *(const float4*)(row_);                                      \
        B1_ = *(const float4*)(row_ + 4);                                  \
        B2_ = *(const float4*)(row_ + 32);                                 \
        B3_ = *(const float4*)(row_ + 36);                                 \
    } while (0)

    if (te > ts) {
        float b2v[3], w3v[3];
        #pragma unroll
        for (int nt = 0; nt < 3; ++nt) {
            int idx = nt * 16 + ln;
            b2v[nt] = (idx < 40) ? b2[idx] * LOG2E : 0.f;
            w3v[nt] = (idx < 40) ? W3[idx] : 0.f;
        }

        const float* qb = q + b * 64;
        float4 q0  = *(const float4*)(qb + g4 * 8);
        float4 q0b = *(const float4*)(qb + g4 * 8 + 4);
        float4 q1  = *(const float4*)(qb + 32 + g4 * 8);
        float4 q1b = *(const float4*)(qb + 32 + g4 * 8 + 4);
        bf16x8 qf0 = pack8(q0, q0b);
        bf16x8 qf1 = pack8(q1, q1b);

        // ---- hinit via 10 MFMA: all A rows = q => every acc row = hinit ----
        float hv[5];
        {
            f32x4 hacc[5];
            #pragma unroll
            for (int nt = 0; nt < 5; ++nt) {
                float bv = b1[nt * 16 + ln] * LOG2E;
                hacc[nt] = (f32x4){bv, bv, bv, bv};
            }
            #pragma unroll
            for (int nt = 0; nt < 5; ++nt) {
                bf16x8 f0 = *(const bf16x8*)&wqff[((0 * 5 + nt) * 64 + l) * 8];
                bf16x8 f1 = *(const bf16x8*)&wqff[((1 * 5 + nt) * 64 + l) * 8];
                hacc[nt] = __builtin_amdgcn_mfma_f32_16x16x32_bf16(qf0, f0, hacc[nt], 0, 0, 0);
                hacc[nt] = __builtin_amdgcn_mfma_f32_16x16x32_bf16(qf1, f1, hacc[nt], 0, 0, 0);
            }
            #pragma unroll
            for (int nt = 0; nt < 5; ++nt) hv[nt] = hacc[nt][0];
        }

        // ---- W_eff = Wk + q (.) Wqk as 10 register B-frags (once/wave) ----
        bf16x8 wf_[2][5];
        #pragma unroll
        for (int s = 0; s < 2; ++s) {
            float qa0 = (s == 0) ? q0.x  : q1.x,  qa1 = (s == 0) ? q0.y  : q1.y;
            float qa2 = (s == 0) ? q0.z  : q1.z,  qa3 = (s == 0) ? q0.w  : q1.w;
            float qb0 = (s == 0) ? q0b.x : q1b.x, qb1 = (s == 0) ? q0b.y : q1b.y;
            float qb2 = (s == 0) ? q0b.z : q1b.z, qb3 = (s == 0) ? q0b.w : q1b.w;
            #pragma unroll
            for (int nt = 0; nt < 5; ++nt) {
                bf16x8 wk = *(const bf16x8*)&w1f[((s * 5 + nt) * 64 + l) * 8];
                bf16x8 wq = *(const bf16x8*)&w1f[(((s + 2) * 5 + nt) * 64 + l) * 8];
                bf16x8 r;
                r[0] = (__bf16)fmaf(qa0, (float)wq[0], (float)wk[0]);
                r[1] = (__bf16)fmaf(qa1, (float)wq[1], (float)wk[1]);
                r[2] = (__bf16)fmaf(qa2, (float)wq[2], (float)wk[2]);
                r[3] = (__bf16)fmaf(qa3, (float)wq[3], (float)wk[3]);
                r[4] = (__bf16)fmaf(qb0, (float)wq[4], (float)wk[4]);
                r[5] = (__bf16)fmaf(qb1, (float)wq[5], (float)wk[5]);
                r[6] = (__bf16)fmaf(qb2, (float)wq[6], (float)wk[6]);
                r[7] = (__bf16)fmaf(qb3, (float)wq[7], (float)wk[7]);
                wf_[s][nt] = r;
            }
        }

#define L1SIG(K0_, K1_, K2_, K3_, DST_) do {                               \
        f32x4 acc[5];                                                      \
        _Pragma("unroll")                                                  \
        for (int nt = 0; nt < 5; ++nt)                                     \
            acc[nt] = (f32x4){hv[nt], hv[nt], hv[nt], hv[nt]};             \
        bf16x8 av0 = pack8(K0_, K1_);                                      \
        bf16x8 av1 = pack8(K2_, K3_);                                      \
        _Pragma("unroll")                                                  \
        for (int nt = 0; nt < 5; ++nt) {                                   \
            acc[nt] = __builtin_amdgcn_mfma_f32_16x16x32_bf16(             \
                av0, wf_[0][nt], acc[nt], 0, 0, 0);                        \
            acc[nt] = __builtin_amdgcn_mfma_f32_16x16x32_bf16(             \
                av1, wf_[1][nt], acc[nt], 0, 0, 0);                        \
        }                                                                  \
        _Pragma("unroll")                                                  \
        for (int nt = 0; nt < 5; ++nt)                                     \
            _Pragma("unroll")                                              \
            for (int r = 0; r < 4; ++r) {                                  \
                float sg = frcp(1.f + fexp2(-acc[nt][r]));                 \
                (DST_)[(g4 * 4 + r) * 104 + nt * 16 + ln] = b16bits(sg);   \
            }                                                              \
    } while (0)

#define AFREAD(SRC_) do {                                                  \
        af0 = *(const bf16x8*)((SRC_) + ln * 104 + g4 * 8);                \
        af1 = *(const bf16x8*)((SRC_) + ln * 104 + 32 + g4 * 8);           \
        af2 = *(const bf16x8*)((SRC_) + ln * 104 + 64 + g4 * 8);           \
    } while (0)

#define L2L3(tile_) do {                                                   \
        f32x4 acc2[3];                                                     \
        _Pragma("unroll")                                                  \
        for (int nt = 0; nt < 3; ++nt)                                     \
            acc2[nt] = (f32x4){b2v[nt], b2v[nt], b2v[nt], b2v[nt]};        \
        _Pragma("unroll")                                                  \
        for (int nt = 0; nt < 3; ++nt) {                                   \
            bf16x8 w0_ = *(const bf16x8*)(w2f + ((0 * 3 + nt) * 64 + l) * 8); \
            bf16x8 w1_ = *(const bf16x8*)(w2f + ((1 * 3 + nt) * 64 + l) * 8); \
            bf16x8 w2_ = *(const bf16x8*)(w2f + ((2 * 3 + nt) * 64 + l) * 8); \
            acc2[nt] = __builtin_amdgcn_mfma_f32_16x16x32_bf16(af0, w0_, acc2[nt], 0, 0, 0); \
            acc2[nt] = __builtin_amdgcn_mfma_f32_16x16x32_bf16(af1, w1_, acc2[nt], 0, 0, 0); \
            acc2[nt] = __builtin_amdgcn_mfma_f32_16x16x32_bf16(af2, w2_, acc2[nt], 0, 0, 0); \
        }                                                                  \
        _Pragma("unroll")                                                  \
        for (int r = 0; r < 4; ++r) {                                      \
            float p = w3v[0] * frcp(1.f + fexp2(-acc2[0][r]))              \
                    + w3v[1] * frcp(1.f + fexp2(-acc2[1][r]))              \
                    + w3v[2] * frcp(1.f + fexp2(-acc2[2][r]));             \
            p += __shfl_xor(p, 1); p += __shfl_xor(p, 2);                  \
            p += __shfl_xor(p, 4); p += __shfl_xor(p, 8);                  \
            if (ln == 0) {                                                 \
                int trow = (tile_) * 16 + g4 * 4 + r;                      \
                if (trow < len)                                            \
                    red[trow] = (p + b3v) * (0.125f * LOG2E);              \
            }                                                              \
        }                                                                  \
    } while (0)

        // ---- dynamic 2-tile pipeline over [ts, te) ----
        float4 A0, A1, A2, A3, C0, C1, C2, C3;
        bf16x8 af0, af1, af2;
        LOADK(ts, A0, A1, A2, A3);
        L1SIG(A0, A1, A2, A3, buf0);
        if (te - ts > 1) {
            LOADK(ts + 1, C0, C1, C2, C3);
            int it = ts;
            #pragma unroll 1
            while (it + 2 < te) {
                AFREAD(buf0);
                L1SIG(C0, C1, C2, C3, buf1);
                LOADK(it + 2, A0, A1, A2, A3);
                L2L3(it);
                AFREAD(buf1);
                L1SIG(A0, A1, A2, A3, buf0);
                LOADK(it + 3, C0, C1, C2, C3);   // over-prefetch clamped
                L2L3(it + 1);
                it += 2;
            }
            if (te - it == 2) {
                AFREAD(buf0);
                L1SIG(C0, C1, C2, C3, buf1);
                L2L3(it);
                AFREAD(buf1);
                L2L3(it + 1);
            } else {   // te - it == 1
                AFREAD(buf0);
                L2L3(it);
            }
        } else {
            AFREAD(buf0);
            L2L3(ts);
        }
#undef L1SIG
#undef AFREAD
#undef L2L3
    }
    __syncthreads();   // all logits in red

    // ---- softmax over red[0..255] (redundant per wave, same values) ----
    float v0 = red[l], v1 = red[64 + l], v2 = red[128 + l], v3 = red[192 + l];
    float m = fmaxf(fmaxf(v0, v1), fmaxf(v2, v3));
    #pragma unroll
    for (int off = 32; off; off >>= 1) m = fmaxf(m, __shfl_xor(m, off));
    float e0 = fexp2(v0 - m), e1 = fexp2(v1 - m);
    float e2 = fexp2(v2 - m), e3 = fexp2(v3 - m);
    float s = (e0 + e1) + (e2 + e3);
    #pragma unroll
    for (int off = 32; off; off >>= 1) s += __shfl_xor(s, off);
    const float is_ = frcp(s);
    // both waves write identical normalized values (benign)
    red[l] = e0 * is_; red[64 + l] = e1 * is_;
    red[128 + l] = e2 * is_; red[192 + l] = e3 * is_;
    // own-wave wrote all 256 -> own reads safe without barrier

    // ---- output: wave w covers t in [w?mid:0, w?obound:mid), lane owns
    //      d-quad [4*ln..4*ln+3], t = start + g4 (mod 4) ----
    {
        const int obound = (len == 0) ? 200 : len;
        const int mid = obound >> 1;
        const int t0 = w ? mid : 0;
        const int t1 = w ? obound : mid;
        float4 oq = {0.f, 0.f, 0.f, 0.f};
        #pragma unroll 4
        for (int t = t0 + g4; t < t1; t += 4) {
            float wgt = red[t];
            float4 kv = *(const float4*)(kb + t * 64 + 4 * ln);
            oq.x = fmaf(wgt, kv.x, oq.x); oq.y = fmaf(wgt, kv.y, oq.y);
            oq.z = fmaf(wgt, kv.z, oq.z); oq.w = fmaf(wgt, kv.w, oq.w);
        }
        oq.x += __shfl_xor(oq.x, 16); oq.x += __shfl_xor(oq.x, 32);
        oq.y += __shfl_xor(oq.y, 16); oq.y += __shfl_xor(oq.y, 32);
        oq.z += __shfl_xor(oq.z, 16); oq.z += __shfl_xor(oq.z, 32);
        oq.w += __shfl_xor(oq.w, 16); oq.w += __shfl_xor(oq.w, 32);
        if (g4 == 0)
            *(float4*)(&opart[w][4 * ln]) = oq;
    }
    __syncthreads();
    if (tid < 64)
        out[b * 64 + tid] = opart[0][tid] + opart[1][tid];
#undef LOADK
}

extern "C" void kernel_launch(void* const* d_in, const int* in_sizes, int n_in,
                              void* d_out, int out_size, void* d_ws, size_t ws_size,
                              hipStream_t stream) {
    const float* q    = (const float*)d_in[0];
    const float* keys = (const float*)d_in[1];
    const int*   kl   = (const int*)d_in[2];
    const float* W1   = (const float*)d_in[3];
    const float* b1   = (const float*)d_in[4];
    const float* W2   = (const float*)d_in[5];
    const float* b2   = (const float*)d_in[6];
    const float* W3   = (const float*)d_in[7];
    const float* b3   = (const float*)d_in[8];

    unsigned short* w1f  = (unsigned short*)d_ws;           // 10240 bf16
    unsigned short* w2f  = w1f + 10240;                     //  4608 bf16
    unsigned short* wqff = w2f + 4608;                      //  5120 bf16

    fold_weights<<<(19968 + 255) / 256, 256, 0, stream>>>(W1, W2, w1f, w2f, wqff);
    din_attn<<<B_, 128, 0, stream>>>(q, keys, kl, w1f, w2f, wqff, b1, b2,
                                     W3, b3, (float*)d_out);
}